// Round 8
// baseline (736.273 us; speedup 1.0000x reference)
//
#include <hip/hip_runtime.h>
#include <hip/hip_bf16.h>

// TKMDAttention on MI355X — round 15: spatial occupancy rework.
//  - S matrix eliminated from LDS: QK^T D-layout keeps each wave's 16 softmax
//    rows in its own lanes, so redistribution is 4 shfl + 3 cndmask per row
//    (sacc stays in regs). Saves 16.6 KB + its 4-way-conflict writes.
//  - LDS region re-plumb: KF over dead qRaw (reg-staged K frags + b1.5),
//    Pl over dead kRaw, VT/WF over dead KF/Pl, O over dead VT.
//    40192 -> 25600 B => 6 blocks/CU by LDS (was 4). launch_bounds (256,5).
//  - VT/Pl stride 72 -> 80 shorts (16B-aligned; PV b128 reads 8-way -> 4-way).
//  - W48 read moved post-b3 (L2-hot) — frees 16 VGPRs held across kernel.
// Everything else = round 14.
// Shapes: b=2, C=384, H=W=128, heads=8, ch=48, crop=8, N=64.
// windowstoimg: token n of window (wy,wx) -> y = wy*8+(wx>>1), x = (wx&1)*64+n.
// top-k rule (tie-exact): keep i for k iff a_i >= k-th largest (ref "a >= kth").

#define HW 16384
#define CDIM 384
#define NHEADS 8
#define CH 48
#define NCHUNK 128

typedef __hip_bfloat16 bf16;
typedef __attribute__((ext_vector_type(8))) short short8;
typedef __attribute__((ext_vector_type(4))) float f32x4;

static __device__ __forceinline__ unsigned short f2bf_bits(float v) {
  bf16 b = __float2bfloat16(v);
  return __builtin_bit_cast(unsigned short, b);
}
static __device__ __forceinline__ float bfbits2f(unsigned short u) {
  return __bfloat162float(__builtin_bit_cast(bf16, u));
}

// DPP move: returns x moved by CTRL (0-fill on invalid when bound_ctrl=true).
template <int CTRL>
static __device__ __forceinline__ float dppf(float x) {
  return __builtin_bit_cast(
      float, __builtin_amdgcn_update_dpp(0, __builtin_bit_cast(int, x), CTRL,
                                         0xF, 0xF, true));
}
// quad_perm(1,0,3,2)=0xB1 (xor1), quad_perm(2,3,0,1)=0x4E (xor2),
// row_ror:8=0x128 (xor8 within 16), row_shl:d=0x100+d (lane i <- i+d, 0-fill).

// ---- weight decompose (qkv + proj in one dispatch) ----
__global__ __launch_bounds__(256) void decomp_all(const float* __restrict__ wq,
                                                  const float* __restrict__ wp,
                                                  unsigned short* __restrict__ qh,
                                                  unsigned short* __restrict__ ql,
                                                  unsigned short* __restrict__ ph,
                                                  unsigned short* __restrict__ pl) {
  const int i = blockIdx.x * 256 + threadIdx.x;
  const int nq = 3 * CDIM * CDIM;
  if (i < nq) {
    const float v = wq[i];
    const unsigned short hb = f2bf_bits(v);
    qh[i] = hb;
    ql[i] = f2bf_bits(v - bfbits2f(hb));
  } else {
    const int k = i - nq;
    if (k < CDIM * CDIM) {
      const float v = wp[k];
      const unsigned short hb = f2bf_bits(v);
      ph[k] = hb;
      pl[k] = f2bf_bits(v - bfbits2f(hb));
    }
  }
}

// ---- transpose src[384][16384] fp32 -> fragment-order bf16 hi/lo ----
// Also zeroes sumsq[768] (block 0) for the following cattn_partial.
__global__ __launch_bounds__(256) void transpose_frag(const float* __restrict__ src,
                                                      short8* __restrict__ dh,
                                                      short8* __restrict__ dl,
                                                      float* __restrict__ sumsq) {
  if (blockIdx.x == 0 && threadIdx.x < 192) {
    const float4 z = {0.f, 0.f, 0.f, 0.f};
    ((float4*)sumsq)[threadIdx.x] = z;
  }
  const int o = blockIdx.x * 256 + threadIdx.x;  // [0, 786432)
  const int ptile = o / 768;
  const int rem = o - ptile * 768;
  const int kc = rem >> 6, lane = rem & 63;
  const int p = ptile * 16 + (lane & 15);
  const int kb = kc * 32 + (lane >> 4) * 8;
  short8 hh, ll;
#pragma unroll
  for (int j = 0; j < 8; j++) {
    float v = src[(size_t)(kb + j) * HW + p];
    unsigned short hb = f2bf_bits(v);
    hh[j] = (short)hb;
    ll[j] = (short)f2bf_bits(v - bfbits2f(hb));
  }
  dh[o] = hh;
  dl[o] = ll;
}

// ---- split-bf16 MFMA GEMM: Out[oc][p] = sum_k W[oc][k] X[k][p], K=384 ----
__global__ __launch_bounds__(256, 4) void gemm_mfma(const unsigned short* __restrict__ Wh,
                                                    const unsigned short* __restrict__ Wl,
                                                    const short8* __restrict__ Xh,
                                                    const short8* __restrict__ Xl,
                                                    float* __restrict__ Out) {
  const int tid = threadIdx.x;
  const int wave = tid >> 6, lane = tid & 63;
  const int lm = lane & 15, lq = lane >> 4;
  const int g = blockIdx.y * 128 + blockIdx.x;  // [0,768)
  const int xcd = g & 7, i = g >> 3;            // bijective remap
  const int bx = xcd * 16 + (i & 15);
  const int by = i >> 4;
  const int p0 = bx * 128;
  const int oc0 = by * 64;
  const int pt0 = bx * 8 + wave * 2;
  f32x4 acc[4][2] = {};
#pragma unroll
  for (int kc = 0; kc < 12; kc++) {
    short8 ah[4], al[4], bh[2], bl[2];
#pragma unroll
    for (int mt = 0; mt < 4; mt++) {
      const size_t off = (size_t)(oc0 + mt * 16 + lm) * 384 + kc * 32 + lq * 8;
      ah[mt] = *reinterpret_cast<const short8*>(Wh + off);
      al[mt] = *reinterpret_cast<const short8*>(Wl + off);
    }
#pragma unroll
    for (int nt = 0; nt < 2; nt++) {
      const size_t idx = (size_t)((pt0 + nt) * 12 + kc) * 64 + lane;
      bh[nt] = Xh[idx];
      bl[nt] = Xl[idx];
    }
#pragma unroll
    for (int mt = 0; mt < 4; mt++)
#pragma unroll
      for (int nt = 0; nt < 2; nt++) {
        acc[mt][nt] = __builtin_amdgcn_mfma_f32_16x16x32_bf16(ah[mt], bh[nt], acc[mt][nt], 0, 0, 0);
        acc[mt][nt] = __builtin_amdgcn_mfma_f32_16x16x32_bf16(ah[mt], bl[nt], acc[mt][nt], 0, 0, 0);
        acc[mt][nt] = __builtin_amdgcn_mfma_f32_16x16x32_bf16(al[mt], bh[nt], acc[mt][nt], 0, 0, 0);
      }
  }
#pragma unroll
  for (int mt = 0; mt < 4; mt++)
#pragma unroll
    for (int nt = 0; nt < 2; nt++)
#pragma unroll
      for (int r = 0; r < 4; r++) {
        const int oc = oc0 + mt * 16 + lq * 4 + r;
        const int p = p0 + (wave * 2 + nt) * 16 + lm;
        Out[(size_t)oc * HW + p] = acc[mt][nt][r];
      }
}

// ---- depthwise 3x3 pad1, 384 channels; 4 pixels/thread, float4 loads ----
__global__ __launch_bounds__(256) void dwconv3(const float* __restrict__ A,
                                               const float* __restrict__ wdw,
                                               float* __restrict__ Bq) {
  const int e = blockIdx.x * 256 + threadIdx.x;  // [0, 384*128*32)
  const int x4 = e & 31;
  const int y = (e >> 5) & 127;
  const int ch = e >> 12;
  const int x0 = x4 << 2;
  float w[9];
#pragma unroll
  for (int t = 0; t < 9; t++) w[t] = wdw[ch * 9 + t];
  const float* Ap = A + (size_t)ch * HW;
  float4 acc = {0.f, 0.f, 0.f, 0.f};
#pragma unroll
  for (int ky = 0; ky < 3; ky++) {
    const int yy = y + ky - 1;
    if (yy < 0 || yy > 127) continue;
    const float* row = Ap + yy * 128;
    const float4 c = *(const float4*)(row + x0);
    const float l = (x4 == 0) ? 0.f : row[x0 - 1];
    const float r = (x4 == 31) ? 0.f : row[x0 + 4];
    const float w0 = w[ky * 3], w1 = w[ky * 3 + 1], w2 = w[ky * 3 + 2];
    acc.x += w0 * l + w1 * c.x + w2 * c.y;
    acc.y += w0 * c.x + w1 * c.y + w2 * c.z;
    acc.z += w0 * c.y + w1 * c.z + w2 * c.w;
    acc.w += w0 * c.z + w1 * c.w + w2 * r;
  }
  *(float4*)(Bq + (size_t)e * 4) = acc;
}

// ---- channel-attn partials + fused channel sumsq accumulation ----
__global__ __launch_bounds__(256, 3) void cattn_partial(const float* __restrict__ Bq,
                                                        float* __restrict__ part,
                                                        float* __restrict__ sumsq) {
  __shared__ __align__(16) float qs[48 * 132];
  __shared__ __align__(16) float ks2[48 * 132];
  const int tid = threadIdx.x;
  const int chunk = blockIdx.x, h = blockIdx.y;
  const int p0 = chunk * 128;
#pragma unroll
  for (int i = 0; i < 12; i++) {
    const int s4 = tid + i * 256;
    const int t = s4 >= 1536;
    const int r4 = s4 - t * 1536;
    const int cc = r4 >> 5;
    const int px = (r4 & 31) << 2;
    const float4 v4 = *(const float4*)(Bq + (size_t)(t * CDIM + h * CH + cc) * HW + p0 + px);
    *(float4*)((t ? ks2 : qs) + cc * 132 + px) = v4;
  }
  __syncthreads();
  // fused norms: threads 0..95 reduce one channel's 128 px, atomicAdd
  if (tid < 96) {
    const int t = tid >= 48;
    const int cc = t ? tid - 48 : tid;
    const float* src = (t ? ks2 : qs) + cc * 132;
    float s = 0.f;
#pragma unroll
    for (int p = 0; p < 128; p += 4) {
      const float4 v = *(const float4*)(src + p);
      s += v.x * v.x + v.y * v.y + v.z * v.z + v.w * v.w;
    }
    atomicAdd(&sumsq[t * CDIM + h * CH + cc], s);
  }
  const int tx = tid & 15, ty = tid >> 4;
  const float* qb = qs + (ty * 3) * 132;
  const float* kb = ks2 + (tx * 3) * 132;
  float acc[3][3] = {};
  for (int pl = 0; pl < 128; pl += 4) {
    float4 qv[3], kv[3];
#pragma unroll
    for (int ii = 0; ii < 3; ii++) qv[ii] = *(const float4*)(qb + ii * 132 + pl);
#pragma unroll
    for (int jj = 0; jj < 3; jj++) kv[jj] = *(const float4*)(kb + jj * 132 + pl);
#pragma unroll
    for (int ii = 0; ii < 3; ii++)
#pragma unroll
      for (int jj = 0; jj < 3; jj++)
        acc[ii][jj] += qv[ii].x * kv[jj].x + qv[ii].y * kv[jj].y +
                       qv[ii].z * kv[jj].z + qv[ii].w * kv[jj].w;
  }
  float* rp = part + (size_t)(h * NCHUNK + chunk) * 2304;
#pragma unroll
  for (int ii = 0; ii < 3; ii++)
#pragma unroll
    for (int jj = 0; jj < 3; jj++)
      rp[(ty * 3 + ii) * 48 + tx * 3 + jj] = acc[ii][jj];
}

// ---- channel masked-softmax combine (reduce + inv inline) -> W48 ----
__global__ __launch_bounds__(64) void chan_softmax(
    const float* __restrict__ part, const float* __restrict__ sumsq,
    const float* __restrict__ temp, const float* __restrict__ a1,
    const float* __restrict__ a2, const float* __restrict__ a3,
    const float* __restrict__ a4, float* __restrict__ W48) {
  const int blk = blockIdx.x;  // h*48 + i
  const int i = blk % 48;
  const int h = blk / 48;
  const int lane = threadIdx.x;
  const float t = temp[h];
  float a = -3.0e38f;
  if (lane < 48) {
    const float* pp = part + (size_t)h * NCHUNK * 2304 + i * 48 + lane;
    float r = 0.f;
#pragma unroll 8
    for (int c = 0; c < NCHUNK; c++) r += pp[(size_t)c * 2304];
    const float iq = 1.f / fmaxf(sqrtf(sumsq[h * CH + i]), 1e-12f);
    const float ik = 1.f / fmaxf(sqrtf(sumsq[CDIM + h * CH + lane]), 1e-12f);
    a = t * iq * ik * r;
  }
  float m = a;
  for (int o = 32; o; o >>= 1) m = fmaxf(m, __shfl_xor(m, o));
  float e = (lane < 48) ? expf(a - m) : 0.f;
  int gt = 0;
  for (int j = 0; j < 48; j++) {
    float vj = __shfl(a, j);
    gt += (vj > a) ? 1 : 0;
  }
  const int ksel[4] = {24, 32, 36, 38};
  const float wts[4] = {a1[0], a2[0], a3[0], a4[0]};
  float coef = 0.f;
#pragma unroll
  for (int kk = 0; kk < 4; kk++) {
    float sel = (gt < ksel[kk]) ? e : 0.f;
    for (int o = 32; o; o >>= 1) sel += __shfl_xor(sel, o);
    if (gt < ksel[kk]) coef += wts[kk] / sel;
  }
  if (lane < 48) W48[(size_t)blk * 48 + lane] = e * coef;
}

// W48 frag f -> float offset of its 8-element run in the per-head W48.
static __device__ __forceinline__ int wfrag_off(int f) {
  int nt, n, k0;
  if (f < 192) { nt = f >> 6; const int slot = f & 63; n = slot & 15; k0 = (slot >> 4) * 8; }
  else { const int g2 = f - 192; nt = g2 >> 5; const int slot = g2 & 31; n = slot & 15; k0 = 32 + (slot >> 4) * 8; }
  return (nt * 16 + n) * 48 + k0;
}

// ---- window attention + fused channel-attn output ----
// Block = 1 window, 4 waves. Wave w owns output rows [16w,16w+16).
__global__ __launch_bounds__(256, 5) void spatial_kernel(
    const float* __restrict__ Bq, const float* __restrict__ W48,
    const float* __restrict__ temp, const float* __restrict__ a1,
    const float* __restrict__ a2_, const float* __restrict__ a3,
    const float* __restrict__ a4, float* __restrict__ Cbuf) {
  // LDS (25600 B), lifetime-disjoint by barriers:
  //  [0,12544)      qRaw[64][49] f32     (b1..b1.5)
  //  [12544,25088)  kRaw[64][49] f32     (b1..b1.5)
  //  [0,12288)      KFh/KFl short8[384]  (b2..QK end)
  //  [12544,22784)  P bf16[64][80]       (softmax..pa, wave-local)
  //  [0,15360)      VTh/VTl ush[48][80]  (b3.2..b3.5)
  //  [15360,24576)  WFh/WFl short8[288]  (b3.2..b3.5)
  //  [0,12480)      O[48][65] f32        (post-b3.5)
  //  [25088,25600)  invQ[64], invK[64]
  __shared__ __align__(16) char smem[25600];
  float* qRaw = (float*)smem;
  float* kRaw = (float*)(smem + 12544);
  short8* KFh = (short8*)smem;
  short8* KFl = (short8*)(smem + 6144);
  bf16* Pl = (bf16*)(smem + 12544);
  unsigned short* VTh = (unsigned short*)smem;
  unsigned short* VTl = (unsigned short*)(smem + 7680);
  short8* WFh = (short8*)(smem + 15360);
  short8* WFl = (short8*)(smem + 19968);
  float* O_lds = (float*)smem;
  float* invQ = (float*)(smem + 25088);
  float* invK = (float*)(smem + 25344);

  const int bid = blockIdx.x;
  const int wid = ((bid & 7) << 8) | (bid >> 3);  // XCD swizzle (2048=8*256)
  const int wx = wid & 15, wy = (wid >> 4) & 15;
  const int head = wid >> 8;
  const int tid = threadIdx.x;
  const int lane = tid & 63, w = tid >> 6;
  const int lm = lane & 15, lq = lane >> 4;
  const int ybase = wy * 8, xbase = wx * 8;
  const int y_out = wy * 8 + (wx >> 1);      // windowstoimg store row
  const int x0 = (wx & 1) * 64;              // windowstoimg store col base
  const size_t hb = (size_t)(head * CH) * HW;
  const float* wsrc = W48 + (size_t)head * 2304;

  // phase 0: q,k windows -> raw LDS (float4 global loads)
#pragma unroll
  for (int i = 0; i < 6; i++) {
    const int s4 = tid + i * 256;  // [0,1536)
    const int t = s4 >= 768;
    const int r4 = s4 - t * 768;
    const int cc = r4 >> 4, nq = r4 & 15;
    const int n = nq * 4;
    const int y = ybase + (n >> 3), x = xbase + (n & 7);
    const float4 v4 = *(const float4*)(Bq + (size_t)(t * CDIM) * HW + hb +
                                       (size_t)cc * HW + y * 128 + x);
    float* dst = (t ? kRaw : qRaw) + n * 49 + cc;
    dst[0] = v4.x; dst[49] = v4.y; dst[98] = v4.z; dst[147] = v4.w;
  }
  __syncthreads();  // b1

  // V(gather) float4 loads for PV; Vc per-lane strided loads (cattn A-frag
  // source: 16 channel values at this lane's STORE pixel). All issued early.
  float4 vv[3];
#pragma unroll
  for (int i = 0; i < 3; i++) {
    const int e4 = tid + i * 256;  // [0,768)
    const int cc = e4 >> 4, n = (e4 & 15) * 4;
    const int y = ybase + (n >> 3), x = xbase + (n & 7);
    vv[i] = *(const float4*)(Bq + (size_t)(2 * CDIM) * HW + hb +
                             (size_t)cc * HW + y * 128 + x);
  }
  float af[16];
  {
    const int px = y_out * 128 + x0 + (w * 16 + lm);
    const float* vpl = Bq + (size_t)(2 * CDIM) * HW + hb + px;
#pragma unroll
    for (int ks = 0; ks < 2; ks++)
#pragma unroll
      for (int j = 0; j < 8; j++) {
        const int ch = ks * 32 + lq * 8 + j;
        af[ks * 8 + j] = (ch < 48) ? vpl[(size_t)ch * HW] : 0.f;
      }
  }

  // norms (threads 0..127); temperature folded into invQ
  if (tid < 128) {
    const int t = tid >> 6, n = tid & 63;
    const float* src = (t ? kRaw : qRaw) + n * 49;
    float ssum = 0.f;
#pragma unroll
    for (int cc = 0; cc < 48; cc++) { float v = src[cc]; ssum += v * v; }
    const float iv = 1.f / fmaxf(sqrtf(ssum), 1e-12f);
    if (t) invK[n] = iv; else invQ[n] = iv * temp[head];
  }

  // K frags -> regs (reads kRaw; written to LDS after b1.5)
  short8 kh0r, kl0r, kh1r, kl1r;
  {
    const int nt = tid >> 6, slot = tid & 63;
    const float* src = kRaw + (nt * 16 + (slot & 15)) * 49 + (slot >> 4) * 8;
#pragma unroll
    for (int j = 0; j < 8; j++) {
      const float v = src[j];
      const unsigned short hbk = f2bf_bits(v);
      kh0r[j] = (short)hbk;
      kl0r[j] = (short)f2bf_bits(v - bfbits2f(hbk));
    }
  }
  if (tid < 128) {
    const int nt = tid >> 5, slot = tid & 31;
    const float* src = kRaw + (nt * 16 + (slot & 15)) * 49 + 32 + (slot >> 4) * 8;
#pragma unroll
    for (int j = 0; j < 8; j++) {
      const float v = src[j];
      const unsigned short hbk = f2bf_bits(v);
      kh1r[j] = (short)hbk;
      kl1r[j] = (short)f2bf_bits(v - bfbits2f(hbk));
    }
  }

  // Q A-frags: Q[w*16+lm][ks*32+lq*8+j] (reads qRaw)
  short8 qh[2], ql[2];
#pragma unroll
  for (int ks = 0; ks < 2; ks++) {
    const int ch0 = ks * 32 + lq * 8;
    const float* qp = qRaw + (w * 16 + lm) * 49 + ch0;
#pragma unroll
    for (int j = 0; j < 8; j++) {
      const float v = (ch0 < 48) ? qp[j] : 0.f;
      const unsigned short hbts = f2bf_bits(v);
      qh[ks][j] = (short)hbts;
      ql[ks][j] = (short)f2bf_bits(v - bfbits2f(hbts));
    }
  }
  __syncthreads();  // b1.5: all raw reads + norms done; raw regions die

  // KF writes over dead qRaw
  KFh[tid] = kh0r;
  KFl[tid] = kl0r;
  if (tid < 128) { KFh[256 + tid] = kh1r; KFl[256 + tid] = kl1r; }
  __syncthreads();  // b2: KF + invs ready

  // QK^T: 24 MFMAs (hi*hi + hi*lo + lo*hi per ks)
  f32x4 sacc[4] = {};
#pragma unroll
  for (int nt = 0; nt < 4; nt++) {
    const short8 kh0 = KFh[nt * 64 + lane];
    const short8 kl0 = KFl[nt * 64 + lane];
    sacc[nt] = __builtin_amdgcn_mfma_f32_16x16x32_bf16(qh[0], kh0, sacc[nt], 0, 0, 0);
    sacc[nt] = __builtin_amdgcn_mfma_f32_16x16x32_bf16(qh[0], kl0, sacc[nt], 0, 0, 0);
    sacc[nt] = __builtin_amdgcn_mfma_f32_16x16x32_bf16(ql[0], kh0, sacc[nt], 0, 0, 0);
    short8 kh1 = {0, 0, 0, 0, 0, 0, 0, 0}, kl1 = {0, 0, 0, 0, 0, 0, 0, 0};
    if (lane < 32) { kh1 = KFh[256 + nt * 32 + lane]; kl1 = KFl[256 + nt * 32 + lane]; }
    sacc[nt] = __builtin_amdgcn_mfma_f32_16x16x32_bf16(qh[1], kh1, sacc[nt], 0, 0, 0);
    sacc[nt] = __builtin_amdgcn_mfma_f32_16x16x32_bf16(qh[1], kl1, sacc[nt], 0, 0, 0);
    sacc[nt] = __builtin_amdgcn_mfma_f32_16x16x32_bf16(ql[1], kh1, sacc[nt], 0, 0, 0);
  }

  // softmax + top-k per row, S redistributed from sacc via shuffles.
  // Row R=w*16+rr lives in lanes (lqR=rr>>2, lm'): col c in lane lqR*16+(c&15),
  // register sacc[c>>4][rr&3].
  const float wts[4] = {a1[0], a2_[0], a3[0], a4[0]};
  const int sidx[4] = {32, 22, 16, 13};  // 64-k for k in {32,42,48,51}
  const float ikl = invK[lane];
#pragma unroll
  for (int rr = 0; rr < 16; rr++) {
    const int lqR = rr >> 2, rR = rr & 3;
    const int srcl = lqR * 16 + lm;
    const float t0 = __shfl(sacc[0][rR], srcl);
    const float t1 = __shfl(sacc[1][rR], srcl);
    const float t2 = __shfl(sacc[2][rR], srcl);
    const float t3 = __shfl(sacc[3][rR], srcl);
    const float araw = (lq == 0) ? t0 : (lq == 1) ? t1 : (lq == 2) ? t2 : t3;
    const float a = araw * invQ[w * 16 + rr] * ikl;
    float s = a;
#pragma unroll
    for (int k2 = 2; k2 <= 64; k2 <<= 1) {
#pragma unroll
      for (int j = k2 >> 1; j > 0; j >>= 1) {
        float o;
        if (j == 1)      o = dppf<0xB1>(s);   // quad_perm xor1
        else if (j == 2) o = dppf<0x4E>(s);   // quad_perm xor2
        else if (j == 8) o = dppf<0x128>(s);  // row_ror:8 == xor8 in 16
        else             o = __shfl_xor(s, j);
        const bool up = ((lane & k2) == 0);
        const bool lower = ((lane & j) == 0);
        const float mn = fminf(s, o), mx = fmaxf(s, o);
        s = (lower == up) ? mn : mx;
      }
    }
    const float m = __shfl(s, 63);
    float v = __expf(s - m);
    v += dppf<0x101>(v);  // row_shl:1
    v += dppf<0x102>(v);  // row_shl:2
    v += dppf<0x104>(v);  // row_shl:4
    v += dppf<0x108>(v);  // row_shl:8
    const float t1s = __shfl(v, 16), t2s = __shfl(v, 32), t3s = __shfl(v, 48);
    const float beyond =
        (lq == 0) ? (t1s + t2s + t3s) : (lq == 1) ? (t2s + t3s) : (lq == 2) ? t3s : 0.f;
    const float suf = v + beyond;  // suf[l] = sum_{j>=l} exp(s_j - m)
    const float e = __expf(a - m);
    float coef = 0.f;
#pragma unroll
    for (int kk = 0; kk < 4; kk++) {
      const float tk = __shfl(s, sidx[kk]);
      const float Sk = __shfl(suf, sidx[kk]);
      if (a >= tk) coef += wts[kk] * __builtin_amdgcn_rcpf(Sk);
    }
    Pl[(w * 16 + rr) * 80 + lane] = __float2bfloat16(e * coef);
  }
  // P frags: own-wave rows, wave-local LDS RAW (no barrier needed)
  short8 pa[2];
#pragma unroll
  for (int ks = 0; ks < 2; ks++)
    pa[ks] = *reinterpret_cast<const short8*>(&Pl[(w * 16 + lm) * 80 + ks * 32 + lq * 8]);
  __syncthreads();  // b3: all waves past QK/softmax/pa; KF + Pl regions die

  // V(gather) regs -> split-bf16 frag-layout VT[ch][80] (B-operand for PV)
#pragma unroll
  for (int i = 0; i < 3; i++) {
    const int e4 = tid + i * 256;
    const int cc = e4 >> 4, n = (e4 & 15) * 4;
    const float v0 = vv[i].x, v1 = vv[i].y, v2 = vv[i].z, v3 = vv[i].w;
    const unsigned short h0 = f2bf_bits(v0), h1 = f2bf_bits(v1),
                         h2 = f2bf_bits(v2), h3 = f2bf_bits(v3);
    const ushort4 hh = {h0, h1, h2, h3};
    const ushort4 ll = {f2bf_bits(v0 - bfbits2f(h0)), f2bf_bits(v1 - bfbits2f(h1)),
                        f2bf_bits(v2 - bfbits2f(h2)), f2bf_bits(v3 - bfbits2f(h3))};
    *(ushort4*)(VTh + cc * 80 + n) = hh;
    *(ushort4*)(VTl + cc * 80 + n) = ll;
  }
  // WF: W48 (L2-hot) -> split-bf16 frags over dead Pl region
  {
    const int off = wfrag_off(tid);
    const float4 aw = *(const float4*)(wsrc + off);
    const float4 bw = *(const float4*)(wsrc + off + 4);
    const float wv[8] = {aw.x, aw.y, aw.z, aw.w, bw.x, bw.y, bw.z, bw.w};
    short8 hh, ll;
#pragma unroll
    for (int j = 0; j < 8; j++) {
      const unsigned short hbw = f2bf_bits(wv[j]);
      hh[j] = (short)hbw;
      ll[j] = (short)f2bf_bits(wv[j] - bfbits2f(hbw));
    }
    WFh[tid] = hh;
    WFl[tid] = ll;
  }
  if (tid < 32) {
    const int off = wfrag_off(256 + tid);
    const float4 aw = *(const float4*)(wsrc + off);
    const float4 bw = *(const float4*)(wsrc + off + 4);
    const float wv[8] = {aw.x, aw.y, aw.z, aw.w, bw.x, bw.y, bw.z, bw.w};
    short8 hh, ll;
#pragma unroll
    for (int j = 0; j < 8; j++) {
      const unsigned short hbw = f2bf_bits(wv[j]);
      hh[j] = (short)hbw;
      ll[j] = (short)f2bf_bits(wv[j] - bfbits2f(hbw));
    }
    WFh[256 + tid] = hh;
    WFl[256 + tid] = ll;
  }
  // Vc A-frags from the early strided loads (reg-only)
  short8 a2h[2], a2l[2];
#pragma unroll
  for (int ks = 0; ks < 2; ks++)
#pragma unroll
    for (int j = 0; j < 8; j++) {
      const float v = af[ks * 8 + j];
      const unsigned short hv = f2bf_bits(v);
      a2h[ks][j] = (short)hv;
      a2l[ks][j] = (short)f2bf_bits(v - bfbits2f(hv));
    }
  __syncthreads();  // b3.2: VT + WF ready

  f32x4 oacc[3] = {};
#pragma unroll
  for (int nt = 0; nt < 3; nt++) {
    const int chv = nt * 16 + lm;
    // PV: 4 MFMAs
#pragma unroll
    for (int ks = 0; ks < 2; ks++) {
      const short8 vh = *reinterpret_cast<const short8*>(VTh + chv * 80 + ks * 32 + lq * 8);
      const short8 vl = *reinterpret_cast<const short8*>(VTl + chv * 80 + ks * 32 + lq * 8);
      oacc[nt] = __builtin_amdgcn_mfma_f32_16x16x32_bf16(pa[ks], vh, oacc[nt], 0, 0, 0);
      oacc[nt] = __builtin_amdgcn_mfma_f32_16x16x32_bf16(pa[ks], vl, oacc[nt], 0, 0, 0);
    }
    // cattn (W48 . Vc): 6 MFMAs (3-term split x 2 ks)
    {
      const short8 wh0 = WFh[nt * 64 + lane];
      const short8 wl0 = WFl[nt * 64 + lane];
      oacc[nt] = __builtin_amdgcn_mfma_f32_16x16x32_bf16(a2h[0], wh0, oacc[nt], 0, 0, 0);
      oacc[nt] = __builtin_amdgcn_mfma_f32_16x16x32_bf16(a2h[0], wl0, oacc[nt], 0, 0, 0);
      oacc[nt] = __builtin_amdgcn_mfma_f32_16x16x32_bf16(a2l[0], wh0, oacc[nt], 0, 0, 0);
      short8 wh1 = {0, 0, 0, 0, 0, 0, 0, 0}, wl1 = {0, 0, 0, 0, 0, 0, 0, 0};
      if (lane < 32) { wh1 = WFh[192 + nt * 32 + lane]; wl1 = WFl[192 + nt * 32 + lane]; }
      oacc[nt] = __builtin_amdgcn_mfma_f32_16x16x32_bf16(a2h[1], wh1, oacc[nt], 0, 0, 0);
      oacc[nt] = __builtin_amdgcn_mfma_f32_16x16x32_bf16(a2h[1], wl1, oacc[nt], 0, 0, 0);
      oacc[nt] = __builtin_amdgcn_mfma_f32_16x16x32_bf16(a2l[1], wh1, oacc[nt], 0, 0, 0);
    }
  }
  __syncthreads();  // b3.5: all VT/WF reads done

  // O -> LDS transposed [ch][store-idx] (over dead VT region)
#pragma unroll
  for (int nt = 0; nt < 3; nt++)
#pragma unroll
    for (int r = 0; r < 4; r++)
      O_lds[(nt * 16 + lm) * 65 + w * 16 + lq * 4 + r] = oacc[nt][r];
  __syncthreads();  // b4

  // pure store, float4-coalesced (spatial + channel attn fused)
#pragma unroll
  for (int i = 0; i < 3; i++) {
    const int s4 = tid + i * 256;
    const int cc = s4 >> 4, n = (s4 & 15) * 4;
    const float* op = O_lds + cc * 65 + n;
    const float4 o4 = {op[0], op[1], op[2], op[3]};
    *(float4*)(Cbuf + ((size_t)(head * CH + cc) * 128 + y_out) * 128 + x0 + n) = o4;
  }
}

// ---------------- launch ----------------
extern "C" void kernel_launch(void* const* d_in, const int* in_sizes, int n_in,
                              void* d_out, int out_size, void* d_ws, size_t ws_size,
                              hipStream_t stream) {
  const float* x = (const float*)d_in[0];
  const float* w_qkv = (const float*)d_in[1];
  const float* w_dw = (const float*)d_in[2];
  const float* w_proj = (const float*)d_in[3];
  const float* temp = (const float*)d_in[4];
  const float* a1 = (const float*)d_in[5];
  const float* a2 = (const float*)d_in[6];
  const float* a3 = (const float*)d_in[7];
  const float* a4 = (const float*)d_in[8];
  float* out = (float*)d_out;

  // ws layout (bytes):
  //   [0,         9437184)  cattn_part f32 (128*8*2304)
  //   [9437184,   9510912)  W48 f32
  //   [9510912,   9513984)  sumsq f32 (768)
  //   [9513984,  10398720)  wqkv_h bf16 bits (1152x384)
  //   [10398720, 11283456)  wqkv_l
  //   [11283456, 11578368)  wproj_h (384x384)
  //   [11578368, 11873280)  wproj_l
  //   [11873280, 87370752)  Bq f32 (1152x16384) = 75.5 MB
  //     Xtg hi/lo in Bq v-third during qkv phase; Ctg hi/lo in q-third for proj.
  // Peak 87.4 MB (<= proven 89.4 MB).
  char* ws = (char*)d_ws;
  float* cattn_part = (float*)ws;
  float* W48 = (float*)(ws + 9437184);
  float* sumsq = (float*)(ws + 9510912);
  unsigned short* wqkv_h = (unsigned short*)(ws + 9513984);
  unsigned short* wqkv_l = (unsigned short*)(ws + 10398720);
  unsigned short* wproj_h = (unsigned short*)(ws + 11283456);
  unsigned short* wproj_l = (unsigned short*)(ws + 11578368);
  float* Bq = (float*)(ws + 11873280);
  short8* Xtgh = (short8*)(ws + 11873280 + (size_t)2 * CDIM * HW * 4);
  short8* Xtgl = (short8*)(ws + 11873280 + (size_t)2 * CDIM * HW * 4 + 12582912);
  short8* Ctgh = (short8*)(ws + 11873280);
  short8* Ctgl = (short8*)(ws + 11873280 + 12582912);

  decomp_all<<<(4 * CDIM * CDIM + 255) / 256, 256, 0, stream>>>(
      w_qkv, w_proj, wqkv_h, wqkv_l, wproj_h, wproj_l);

  for (int b = 0; b < 2; b++) {
    const float* xb = x + (size_t)b * CDIM * HW;
    float* ob = out + (size_t)b * CDIM * HW;

    transpose_frag<<<3072, 256, 0, stream>>>(xb, Xtgh, Xtgl, sumsq);  // zeroes sumsq
    for (int t = 0; t < 3; t++) {
      gemm_mfma<<<dim3(HW / 128, CDIM / 64), 256, 0, stream>>>(
          wqkv_h + (size_t)t * CDIM * CDIM, wqkv_l + (size_t)t * CDIM * CDIM,
          Xtgh, Xtgl, ob);
      dwconv3<<<(CDIM * HW / 4) / 256, 256, 0, stream>>>(
          ob, w_dw + (size_t)t * CDIM * 9, Bq + (size_t)t * CDIM * HW);
    }

    cattn_partial<<<dim3(NCHUNK, NHEADS), 256, 0, stream>>>(Bq, cattn_part, sumsq);
    chan_softmax<<<NHEADS * 48, 64, 0, stream>>>(cattn_part, sumsq, temp, a1, a2, a3, a4, W48);
    spatial_kernel<<<NHEADS * 256, 256, 0, stream>>>(Bq, W48, temp, a1, a2, a3, a4, ob);

    transpose_frag<<<3072, 256, 0, stream>>>(ob, Ctgh, Ctgl, sumsq);
    gemm_mfma<<<dim3(HW / 128, CDIM / 64), 256, 0, stream>>>(wproj_h, wproj_l,
                                                             Ctgh, Ctgl, ob);
  }

  (void)in_sizes; (void)n_in; (void)out_size; (void)ws_size;
}